// Round 1
// baseline (61.165 us; speedup 1.0000x reference)
//
#include <hip/hip_runtime.h>

// ---------------------------------------------------------------------------
// Joint network: y = relu(f@W1t^T + g@W1p^T + (b1t+b1p)) @ W2^T + b2
// N=32768, K1=1344 (1024 f + 320 g), J=512, KOUT=29. fp32 in/out, bf16 MFMA.
// ---------------------------------------------------------------------------

typedef float  f32x4  __attribute__((ext_vector_type(4)));
typedef short  s16x8  __attribute__((ext_vector_type(8)));   // 8 bf16 = 4 VGPRs

#define N_ROWS   32768
#define K1       1344
#define NKS      42            // K1 / 32
#define JDIM     512
#define KOUT     29

// ws layout (elements):
#define WC_ELEMS   (NKS * 4 * 512 * 8)   // 688128 bf16: [ks][kc][j][8]
#define W2C_ELEMS  (64 * 32 * 8)         // 16384 bf16:  [jc][kout][8]

static __device__ __forceinline__ unsigned short f2bf(float x) {
  union { float f; unsigned u; } v; v.f = x;
  unsigned r = v.u + 0x7fffu + ((v.u >> 16) & 1u);   // RNE
  return (unsigned short)(r >> 16);
}

static __device__ __forceinline__ s16x8 cvt8(const f32x4 a, const f32x4 b) {
  s16x8 r;
  r[0] = (short)f2bf(a[0]); r[1] = (short)f2bf(a[1]);
  r[2] = (short)f2bf(a[2]); r[3] = (short)f2bf(a[3]);
  r[4] = (short)f2bf(b[0]); r[5] = (short)f2bf(b[1]);
  r[6] = (short)f2bf(b[2]); r[7] = (short)f2bf(b[3]);
  return r;
}

// ---------------------------------------------------------------------------
// Prep: build bf16 weight images in ws.
// Wc  [ks][kc][j][8]  : element (j, c=ks*32+kc*8+e) of concat(W1t, W1p)
// W2c [jc][kout32][8] : element (kout, j=jc*8+e) of W2 (rows 29..31 zero)
// bc[512] = b1t+b1p ; b2c[32] (pad zero)
// ---------------------------------------------------------------------------
__global__ __launch_bounds__(512) void prep_kernel(
    const float* __restrict__ W1t, const float* __restrict__ b1t,
    const float* __restrict__ W1p, const float* __restrict__ b1p,
    const float* __restrict__ W2,  const float* __restrict__ b2,
    unsigned short* __restrict__ Wc, unsigned short* __restrict__ W2c,
    float* __restrict__ bc, float* __restrict__ b2c) {
  int idx = blockIdx.x * 512 + threadIdx.x;
  if (idx < WC_ELEMS) {
    int e  = idx & 7;
    int j  = (idx >> 3) & 511;
    int kc = (idx >> 12) & 3;
    int ks = idx >> 14;
    int c  = ks * 32 + kc * 8 + e;
    float v = (c < 1024) ? W1t[j * 1024 + c] : W1p[j * 320 + (c - 1024)];
    Wc[idx] = f2bf(v);
  }
  if (idx < W2C_ELEMS) {
    int e  = idx & 7;
    int ko = (idx >> 3) & 31;
    int jc = idx >> 8;
    int j  = jc * 8 + e;
    float v = (ko < KOUT) ? W2[ko * 512 + j] : 0.0f;
    W2c[idx] = f2bf(v);
  }
  if (idx < 512) bc[idx]  = b1t[idx] + b1p[idx];
  if (idx < 32)  b2c[idx] = (idx < KOUT) ? b2[idx] : 0.0f;
}

// ---------------------------------------------------------------------------
// Main fused kernel. 256 blocks x 512 threads (8 waves, 2M x 4N wave grid).
// Block tile 128 x 512 (full J). Wave tile 64 x 128.
// LDS: A dbuf [2][4kc][128row][8] @0      (16 KB, XOR-swizzled)
//      B dbuf [2][4kc][512 j][8]  @16384  (64 KB)
//      phase2 h-half [32jc][128row][8] @0 (64 KB, aliases A/B)
//      W2 LDS [64jc][32ko][8]     @81920  (32 KB, persistent)
// ---------------------------------------------------------------------------
__global__ __launch_bounds__(512, 2) void joint_kernel(
    const float* __restrict__ f, const float* __restrict__ g,
    const unsigned short* __restrict__ Wc, const unsigned short* __restrict__ W2c,
    const float* __restrict__ bc, const float* __restrict__ b2c,
    float* __restrict__ out) {
  __shared__ __align__(16) char smem[114688];

  const int tid = threadIdx.x;
  const int l   = tid & 63;
  const int w   = tid >> 6;          // wave 0..7
  const int wm  = w >> 2;            // 0..1  (rows:  wm*64)
  const int wn  = w & 3;             // 0..3  (cols:  wn*128)
  const int m0  = blockIdx.x * 128;

  // phase-1 A staging mapping: row = tid>>2, kc = tid&3 (128B/row coalesced)
  const int srow = tid >> 2;
  const int skc  = tid & 3;
  const float* fRow = f + (size_t)(m0 + srow) * 1024;
  const float* gRow = g + (size_t)(m0 + srow) * 320;
  const unsigned a_wr = (unsigned)(skc * 2048 + ((srow * 16) ^ (skc << 5)));

  // fragment read offsets
  const int kcg = l >> 4;            // 0..3
  const int lc  = l & 15;
  const unsigned a_rd = (unsigned)(kcg * 2048 + ((lc * 16) ^ (kcg << 5)) + wm * 1024);
  const unsigned b_rd = (unsigned)(16384 + kcg * 8192 + lc * 16 + wn * 2048);

  f32x4 acc[4][8];
#pragma unroll
  for (int m = 0; m < 4; m++)
#pragma unroll
    for (int n = 0; n < 8; n++) acc[m][n] = (f32x4)(0.0f);

  f32x4 pa0_0, pa0_1, pa1_0, pa1_1;      // A prefetch ring (depth 2)
  s16x8 pb0, pb1, pb2, pb3;              // B prefetch (depth 1)

#define ISSUE_A(dst0, dst1, T) {                                            \
    int c_ = (T) * 32 + skc * 8;                                            \
    const float* p_ = (c_ < 1024) ? (fRow + c_) : (gRow + (c_ - 1024));     \
    dst0 = *(const f32x4*)p_;                                               \
    dst1 = *(const f32x4*)(p_ + 4);                                         \
  }

#define ISSUE_B(T) {                                                        \
    const char* bs_ = (const char*)Wc + (size_t)(T) * 32768 + tid * 16;     \
    pb0 = *(const s16x8*)(bs_);                                             \
    pb1 = *(const s16x8*)(bs_ + 8192);                                      \
    pb2 = *(const s16x8*)(bs_ + 16384);                                     \
    pb3 = *(const s16x8*)(bs_ + 24576);                                     \
  }

#define WRITE_STAGE(NXTB, srcA0, srcA1) {                                   \
    *(s16x8*)(smem + (NXTB) * 8192 + a_wr) = cvt8(srcA0, srcA1);            \
    char* bd_ = smem + 16384 + (NXTB) * 32768 + tid * 16;                   \
    *(s16x8*)(bd_)         = pb0;                                           \
    *(s16x8*)(bd_ + 8192)  = pb1;                                           \
    *(s16x8*)(bd_ + 16384) = pb2;                                           \
    *(s16x8*)(bd_ + 24576) = pb3;                                           \
  }

#define COMPUTE(CURB) {                                                     \
    s16x8 af[4]; s16x8 bq[8];                                               \
    _Pragma("unroll")                                                       \
    for (int m = 0; m < 4; m++)                                             \
      af[m] = *(const s16x8*)(smem + (CURB) * 8192 + a_rd + m * 256);       \
    _Pragma("unroll")                                                       \
    for (int n = 0; n < 8; n++)                                             \
      bq[n] = *(const s16x8*)(smem + (CURB) * 32768 + b_rd + n * 256);      \
    _Pragma("unroll")                                                       \
    for (int m = 0; m < 4; m++)                                             \
      _Pragma("unroll")                                                     \
      for (int n = 0; n < 8; n++)                                           \
        acc[m][n] = __builtin_amdgcn_mfma_f32_16x16x32_bf16(                \
            af[m], bq[n], acc[m][n], 0, 0, 0);                              \
  }

#define K_ITER(KS, CURB, NXTB, pcur0, pcur1, pnxt0, pnxt1) {                \
    const int ks_ = (KS);                                                   \
    if (ks_ + 2 < NKS) { ISSUE_A(pcur0, pcur1, ks_ + 2); }                  \
    if (ks_ + 1 < NKS) { ISSUE_B(ks_ + 1); }                                \
    COMPUTE(CURB);                                                          \
    if (ks_ + 1 < NKS) { WRITE_STAGE(NXTB, pnxt0, pnxt1); }                 \
    __syncthreads();                                                        \
  }

  // ---- prologue: A(0), A(1), B(0), W2->LDS, write buffer 0 ----
  ISSUE_A(pa0_0, pa0_1, 0);
  ISSUE_A(pa1_0, pa1_1, 1);
  ISSUE_B(0);
  {
    const char* wsrc = (const char*)W2c + tid * 16;
    char* wdst = smem + 81920 + tid * 16;
    *(s16x8*)(wdst)         = *(const s16x8*)(wsrc);
    *(s16x8*)(wdst + 8192)  = *(const s16x8*)(wsrc + 8192);
    *(s16x8*)(wdst + 16384) = *(const s16x8*)(wsrc + 16384);
    *(s16x8*)(wdst + 24576) = *(const s16x8*)(wsrc + 24576);
  }
  {
    *(s16x8*)(smem + a_wr) = cvt8(pa0_0, pa0_1);
    char* bd_ = smem + 16384 + tid * 16;
    *(s16x8*)(bd_)         = pb0;
    *(s16x8*)(bd_ + 8192)  = pb1;
    *(s16x8*)(bd_ + 16384) = pb2;
    *(s16x8*)(bd_ + 24576) = pb3;
  }
  __syncthreads();

  // ---- main K loop: 42 steps, unrolled by 2 for static buffer indices ----
  for (int ks = 0; ks < NKS; ks += 2) {
    K_ITER(ks,     0, 1, pa0_0, pa0_1, pa1_0, pa1_1);
    K_ITER(ks + 1, 1, 0, pa1_0, pa1_1, pa0_0, pa0_1);
  }

  // ---- phase 2: y = relu(h+bias) @ W2^T + b2, h kept on-chip ----
  float bias[8];
#pragma unroll
  for (int n = 0; n < 8; n++) bias[n] = bc[wn * 128 + n * 16 + lc];

  f32x4 acc2[2];
  acc2[0] = (f32x4)(0.0f);
  acc2[1] = (f32x4)(0.0f);

  const unsigned h_rd  = (unsigned)(kcg * 2048 + (w * 16 + lc) * 16);
  const unsigned w2_rd = (unsigned)(81920 + kcg * 512 + lc * 16);
  const unsigned h_wr  = (unsigned)((((wn & 1) * 16) + (lc >> 3)) * 2048 +
                                    (wm * 64 + kcg * 4) * 16 + (l & 7) * 2);
  const int myp = (w >> 1) & 1;

#pragma unroll
  for (int p = 0; p < 2; p++) {
    __syncthreads();                 // h buffer free
    if (myp == p) {
#pragma unroll
      for (int n = 0; n < 8; n++)
#pragma unroll
        for (int m = 0; m < 4; m++)
#pragma unroll
          for (int r = 0; r < 4; r++) {
            float v = acc[m][n][r] + bias[n];
            v = fmaxf(v, 0.0f);
            *(unsigned short*)(smem + h_wr + n * 4096 + m * 256 + r * 16) = f2bf(v);
          }
    }
    __syncthreads();
#pragma unroll
    for (int ks2 = 0; ks2 < 8; ks2++) {
      s16x8 hf = *(const s16x8*)(smem + h_rd + ks2 * 8192);
      s16x8 w0 = *(const s16x8*)(smem + w2_rd + p * 16384 + ks2 * 2048);
      s16x8 w1 = *(const s16x8*)(smem + w2_rd + p * 16384 + ks2 * 2048 + 256);
      acc2[0] = __builtin_amdgcn_mfma_f32_16x16x32_bf16(hf, w0, acc2[0], 0, 0, 0);
      acc2[1] = __builtin_amdgcn_mfma_f32_16x16x32_bf16(hf, w1, acc2[1], 0, 0, 0);
    }
  }

  // ---- epilogue: +b2, store 29 of 32 cols ----
  const float bb0 = b2c[lc];
  const float bb1 = b2c[16 + lc];
  const int orow0 = m0 + w * 16 + kcg * 4;
#pragma unroll
  for (int r = 0; r < 4; r++) {
    const size_t row = (size_t)(orow0 + r);
    out[row * KOUT + lc] = acc2[0][r] + bb0;
    if (lc < KOUT - 16) out[row * KOUT + 16 + lc] = acc2[1][r] + bb1;
  }

#undef ISSUE_A
#undef ISSUE_B
#undef WRITE_STAGE
#undef COMPUTE
#undef K_ITER
}

// ---------------------------------------------------------------------------
extern "C" void kernel_launch(void* const* d_in, const int* in_sizes, int n_in,
                              void* d_out, int out_size, void* d_ws, size_t ws_size,
                              hipStream_t stream) {
  const float* f   = (const float*)d_in[0];
  const float* g   = (const float*)d_in[1];
  const float* W1t = (const float*)d_in[2];
  const float* b1t = (const float*)d_in[3];
  const float* W1p = (const float*)d_in[4];
  const float* b1p = (const float*)d_in[5];
  const float* W2  = (const float*)d_in[6];
  const float* b2  = (const float*)d_in[7];
  float* out = (float*)d_out;

  unsigned short* Wc  = (unsigned short*)d_ws;
  unsigned short* W2c = Wc + WC_ELEMS;
  float* bcp  = (float*)(W2c + W2C_ELEMS);
  float* b2cp = bcp + 512;

  prep_kernel<<<WC_ELEMS / 512, 512, 0, stream>>>(W1t, b1t, W1p, b1p, W2, b2,
                                                  Wc, W2c, bcp, b2cp);
  joint_kernel<<<N_ROWS / 128, 512, 0, stream>>>(f, g, Wc, W2c, bcp, b2cp, out);
}